// Round 3
// baseline (624.694 us; speedup 1.0000x reference)
//
#include <hip/hip_runtime.h>
#include <math.h>

#define NB 64
#define NL 4096
#define ND 512
#define NE 256
#define NV 32000
#define NX 768            // NE + ND
#define CHUNKS 16         // attention L-chunks per batch
#define RPC (NL / CHUNKS) // 256 rows per chunk
#define RPW (RPC / 4)     // 64 rows per wave

// ---------------------------------------------------------------- argmax ----
__global__ void k_argmax(const float* __restrict__ y_prev, int* __restrict__ tok) {
    int b = blockIdx.x, tid = threadIdx.x;
    const float* row = y_prev + (size_t)b * NV;
    float best = -INFINITY; int bi = 0x7fffffff;
    for (int v = tid; v < NV; v += 256) {
        float x = row[v];
        if (x > best || (x == best && v < bi)) { best = x; bi = v; }
    }
    __shared__ float sv[256]; __shared__ int si[256];
    sv[tid] = best; si[tid] = bi;
    __syncthreads();
    for (int s = 128; s > 0; s >>= 1) {
        if (tid < s) {
            float ov = sv[tid + s]; int oi = si[tid + s];
            if (ov > sv[tid] || (ov == sv[tid] && oi < si[tid])) { sv[tid] = ov; si[tid] = oi; }
        }
        __syncthreads();
    }
    if (tid == 0) tok[b] = si[0];
}

// ------------------------------------------------- gate GEMM (x @ W_fiog) ----
// grid (8 col-chunks, 16 batch-groups of 4), 256 thr.
__global__ void k_gates(const float* __restrict__ embedding, const float* __restrict__ out_prev,
                        const int* __restrict__ tok,
                        const float* __restrict__ W_f, const float* __restrict__ W_i,
                        const float* __restrict__ W_g, const float* __restrict__ W_o,
                        float* __restrict__ gatePre /* [4][NB][ND] */) {
    __shared__ float xs[4][NX];
    int tid = threadIdx.x;
    int col = blockIdx.x * 256 + tid;   // 0..2047 (gate-uniform per block)
    int b0  = blockIdx.y * 4;
    for (int e = tid; e < 4 * NX; e += 256) {
        int g = e / NX, k = e - g * NX;
        int b = b0 + g;
        xs[g][k] = (k < NE) ? embedding[(size_t)tok[b] * NE + k]
                            : out_prev[(size_t)b * ND + (k - NE)];
    }
    __syncthreads();
    int gate = col >> 9, d = col & 511;
    const float* W = (gate == 0) ? W_f : (gate == 1) ? W_i : (gate == 2) ? W_g : W_o;
    float a0 = 0, a1 = 0, a2 = 0, a3 = 0;
    for (int k = 0; k < NX; ++k) {
        float w = W[(size_t)k * ND + d];
        a0 += xs[0][k] * w; a1 += xs[1][k] * w; a2 += xs[2][k] * w; a3 += xs[3][k] * w;
    }
    gatePre[((size_t)gate * NB + b0 + 0) * ND + d] = a0;
    gatePre[((size_t)gate * NB + b0 + 1) * ND + d] = a1;
    gatePre[((size_t)gate * NB + b0 + 2) * ND + d] = a2;
    gatePre[((size_t)gate * NB + b0 + 3) * ND + d] = a3;
}

// -------------------------------------------------------- LSTM pointwise ----
// Writes h and c DIRECTLY to their f32 output slots.
__global__ void k_lstm(const float* __restrict__ gatePre, const float* __restrict__ c_prev,
                       const float* __restrict__ b_f, const float* __restrict__ b_i,
                       const float* __restrict__ b_g, const float* __restrict__ b_o,
                       float* __restrict__ h_out, float* __restrict__ c_out) {
    int idx = blockIdx.x * 256 + threadIdx.x;  // 0..32767
    int b = idx >> 9, d = idx & 511;
    float F = gatePre[((size_t)0 * NB + b) * ND + d] + b_f[d];
    float I = gatePre[((size_t)1 * NB + b) * ND + d] + b_i[d];
    float G = gatePre[((size_t)2 * NB + b) * ND + d] + b_g[d];
    float O = gatePre[((size_t)3 * NB + b) * ND + d] + b_o[d];
    float f = 1.f / (1.f + __expf(-F));
    float i = 1.f / (1.f + __expf(-I));
    float g = tanhf(G);
    float o = 1.f / (1.f + __expf(-O));
    float c = c_prev[idx] * f + i * g;
    float h = tanhf(c) * o;
    h_out[idx] = h;
    c_out[idx] = c;
}

// ------------------------------------------------------- b = h @ W_e ---------
__global__ void k_we(const float* __restrict__ h, const float* __restrict__ W_e,
                     float* __restrict__ bvec) {
    __shared__ float hs[4][ND];
    int tid = threadIdx.x, col = blockIdx.x * 256 + tid, b0 = blockIdx.y * 4;
    for (int e = tid; e < 4 * ND; e += 256) { int g = e >> 9, k = e & 511; hs[g][k] = h[(size_t)(b0 + g) * ND + k]; }
    __syncthreads();
    float a0 = 0, a1 = 0, a2 = 0, a3 = 0;
    for (int k = 0; k < ND; ++k) {
        float w = W_e[(size_t)k * ND + col];
        a0 += hs[0][k] * w; a1 += hs[1][k] * w; a2 += hs[2][k] * w; a3 += hs[3][k] * w;
    }
    bvec[(size_t)(b0 + 0) * ND + col] = a0;
    bvec[(size_t)(b0 + 1) * ND + col] = a1;
    bvec[(size_t)(b0 + 2) * ND + col] = a2;
    bvec[(size_t)(b0 + 3) * ND + col] = a3;
}

// --------------------------- fused attention: online softmax + context ------
// grid NB*CHUNKS blocks, 256 thr (4 waves). Reads featureGrid exactly once.
__global__ void k_attn(const float* __restrict__ fg, const float* __restrict__ bvec,
                       float* __restrict__ partM, float* __restrict__ partS,
                       float* __restrict__ partZ) {
    int blk = blockIdx.x;
    int b = blk / CHUNKS, chunk = blk - b * CHUNKS;
    int tid = threadIdx.x, wave = tid >> 6, lane = tid & 63;
    float4 bs0 = ((const float4*)(bvec + (size_t)b * ND + lane * 8))[0];
    float4 bs1 = ((const float4*)(bvec + (size_t)b * ND + lane * 8))[1];
    const float* rowp = fg + ((size_t)b * NL + (size_t)chunk * RPC + wave * RPW) * ND + lane * 8;
    float m = -INFINITY, s = 0.f;
    float z0 = 0, z1 = 0, z2 = 0, z3 = 0, z4 = 0, z5 = 0, z6 = 0, z7 = 0;
    float4 v0 = ((const float4*)rowp)[0];
    float4 v1 = ((const float4*)rowp)[1];
    for (int r = 0; r < RPW; ++r) {
        float4 n0 = v0, n1 = v1;
        if (r + 1 < RPW) {  // prefetch next row
            const float* np = rowp + ND;
            n0 = ((const float4*)np)[0];
            n1 = ((const float4*)np)[1];
        }
        float e = v0.x * bs0.x + v0.y * bs0.y + v0.z * bs0.z + v0.w * bs0.w
                + v1.x * bs1.x + v1.y * bs1.y + v1.z * bs1.z + v1.w * bs1.w;
        #pragma unroll
        for (int off = 32; off > 0; off >>= 1) e += __shfl_xor(e, off, 64);
        // branchless online-softmax update
        float mn = fmaxf(m, e);
        float sc = __expf(m - mn);   // m=-inf -> 0
        float w  = __expf(e - mn);
        s = s * sc + w;
        z0 = z0 * sc + w * v0.x; z1 = z1 * sc + w * v0.y;
        z2 = z2 * sc + w * v0.z; z3 = z3 * sc + w * v0.w;
        z4 = z4 * sc + w * v1.x; z5 = z5 * sc + w * v1.y;
        z6 = z6 * sc + w * v1.z; z7 = z7 * sc + w * v1.w;
        m = mn;
        rowp += ND; v0 = n0; v1 = n1;
    }
    __shared__ float wm[4], wsum[4], wz[4][ND];
    float* zp = &wz[wave][lane * 8];
    zp[0] = z0; zp[1] = z1; zp[2] = z2; zp[3] = z3; zp[4] = z4; zp[5] = z5; zp[6] = z6; zp[7] = z7;
    if (lane == 0) { wm[wave] = m; wsum[wave] = s; }
    __syncthreads();
    float M = fmaxf(fmaxf(wm[0], wm[1]), fmaxf(wm[2], wm[3]));
    float e0 = __expf(wm[0] - M), e1 = __expf(wm[1] - M), e2 = __expf(wm[2] - M), e3 = __expf(wm[3] - M);
    if (tid == 0) {
        partM[blk] = M;
        partS[blk] = wsum[0] * e0 + wsum[1] * e1 + wsum[2] * e2 + wsum[3] * e3;
    }
    for (int d = tid; d < ND; d += 256)
        partZ[(size_t)blk * ND + d] = wz[0][d] * e0 + wz[1][d] * e1 + wz[2][d] * e2 + wz[3][d] * e3;
}

// ---------------------------------------------- combine chunk partials → z --
__global__ void k_zcomb(const float* __restrict__ partM, const float* __restrict__ partS,
                        const float* __restrict__ partZ, float* __restrict__ z) {
    int b = blockIdx.x, tid = threadIdx.x;
    float M = -INFINITY;
    #pragma unroll
    for (int j = 0; j < CHUNKS; ++j) M = fmaxf(M, partM[b * CHUNKS + j]);
    float w[CHUNKS]; float S = 0.f;
    #pragma unroll
    for (int j = 0; j < CHUNKS; ++j) { w[j] = __expf(partM[b * CHUNKS + j] - M); S += partS[b * CHUNKS + j] * w[j]; }
    float inv = 1.f / S;
    for (int d = tid; d < ND; d += 256) {
        float acc = 0.f;
        #pragma unroll
        for (int j = 0; j < CHUNKS; ++j) acc += w[j] * partZ[((size_t)b * CHUNKS + j) * ND + d];
        z[(size_t)b * ND + d] = acc * inv;
    }
}

// ------------------------------------------- out = tanh([h,z] @ W_out) ------
// Writes out directly to its f32 output slot.
__global__ void k_out(const float* __restrict__ h, const float* __restrict__ z,
                      const float* __restrict__ W_out, float* __restrict__ out_f32) {
    __shared__ float hzs[4][2 * ND];
    int tid = threadIdx.x, col = blockIdx.x * 256 + tid, b0 = blockIdx.y * 4;
    for (int e = tid; e < 4 * 2 * ND; e += 256) {
        int g = e >> 10, k = e & 1023; int b = b0 + g;
        hzs[g][k] = (k < ND) ? h[(size_t)b * ND + k] : z[(size_t)b * ND + (k - ND)];
    }
    __syncthreads();
    float a0 = 0, a1 = 0, a2 = 0, a3 = 0;
    for (int k = 0; k < 2 * ND; ++k) {
        float w = W_out[(size_t)k * ND + col];
        a0 += hzs[0][k] * w; a1 += hzs[1][k] * w; a2 += hzs[2][k] * w; a3 += hzs[3][k] * w;
    }
    out_f32[(size_t)(b0 + 0) * ND + col] = tanhf(a0);
    out_f32[(size_t)(b0 + 1) * ND + col] = tanhf(a1);
    out_f32[(size_t)(b0 + 2) * ND + col] = tanhf(a2);
    out_f32[(size_t)(b0 + 3) * ND + col] = tanhf(a3);
}

// --------------------------------------------- logits = out @ W_y -----------
// Writes f32 logits directly into the y slot of d_out (softmax runs in place).
__global__ void k_logits(const float* __restrict__ outb, const float* __restrict__ W_y,
                         float* __restrict__ ylog) {
    __shared__ float os[64][64];  // [dd][b]
    int tid = threadIdx.x;
    int bg = tid >> 5;            // 0..7 -> batches bg*8..bg*8+7
    int cg = tid & 31;            // cols c0..c0+3
    int c0 = blockIdx.x * 128 + cg * 4;
    float acc[8][4];
    #pragma unroll
    for (int i = 0; i < 8; ++i)
        #pragma unroll
        for (int j = 0; j < 4; ++j) acc[i][j] = 0.f;
    for (int dt = 0; dt < 8; ++dt) {
        if (dt) __syncthreads();
        for (int e = tid; e < 4096; e += 256) {
            int dd = e >> 6, b = e & 63;
            os[dd][b] = outb[(size_t)b * ND + dt * 64 + dd];
        }
        __syncthreads();
        for (int dd = 0; dd < 64; ++dd) {
            float4 wv = *(const float4*)&W_y[(size_t)(dt * 64 + dd) * NV + c0];
            float4 o0 = *(const float4*)&os[dd][bg * 8];
            float4 o1 = *(const float4*)&os[dd][bg * 8 + 4];
            const float ob[8] = {o0.x, o0.y, o0.z, o0.w, o1.x, o1.y, o1.z, o1.w};
            const float wj[4] = {wv.x, wv.y, wv.z, wv.w};
            #pragma unroll
            for (int i = 0; i < 8; ++i)
                #pragma unroll
                for (int j = 0; j < 4; ++j) acc[i][j] += ob[i] * wj[j];
        }
    }
    #pragma unroll
    for (int i = 0; i < 8; ++i) {
        float4 st = make_float4(acc[i][0], acc[i][1], acc[i][2], acc[i][3]);
        *(float4*)&ylog[(size_t)(bg * 8 + i) * NV + c0] = st;
    }
}

// --------------------------------- softmax in place on f32 logits -> f32 y --
__global__ void k_softmax(float* __restrict__ y) {
    int b = blockIdx.x, tid = threadIdx.x;
    float* row = y + (size_t)b * NV;
    __shared__ float red[256];
    float m = -INFINITY;
    for (int v = tid; v < NV; v += 256) m = fmaxf(m, row[v]);
    red[tid] = m; __syncthreads();
    for (int s = 128; s > 0; s >>= 1) { if (tid < s) red[tid] = fmaxf(red[tid], red[tid + s]); __syncthreads(); }
    float M = red[0];
    __syncthreads();
    float sum = 0.f;
    for (int v = tid; v < NV; v += 256) sum += __expf(row[v] - M);
    red[tid] = sum; __syncthreads();
    for (int s = 128; s > 0; s >>= 1) { if (tid < s) red[tid] += red[tid + s]; __syncthreads(); }
    float inv = 1.f / red[0];
    for (int v = tid; v < NV; v += 256) row[v] = __expf(row[v] - M) * inv;
}

// ---------------------------------------------------------------------------
extern "C" void kernel_launch(void* const* d_in, const int* in_sizes, int n_in,
                              void* d_out, int out_size, void* d_ws, size_t ws_size,
                              hipStream_t stream) {
    (void)in_sizes; (void)n_in; (void)out_size; (void)d_ws; (void)ws_size;
    const float* featureGrid = (const float*)d_in[0];
    const float* y_prev      = (const float*)d_in[1];
    const float* out_prev    = (const float*)d_in[2];
    // d_in[3] = h_prev (unused by the reference)
    const float* c_prev      = (const float*)d_in[4];
    const float* embedding   = (const float*)d_in[5];
    const float* W_f = (const float*)d_in[6];
    const float* W_i = (const float*)d_in[7];
    const float* W_g = (const float*)d_in[8];
    const float* W_o = (const float*)d_in[9];
    const float* b_f = (const float*)d_in[10];
    const float* b_i = (const float*)d_in[11];
    const float* b_g = (const float*)d_in[12];
    const float* b_o = (const float*)d_in[13];
    const float* W_e   = (const float*)d_in[14];
    const float* W_out = (const float*)d_in[15];
    const float* W_y   = (const float*)d_in[16];

    // d_out: flat f32, return order: y [64*32000] | out [64*512] | h | c
    float* y_f32   = (float*)d_out;                 // 2,048,000 floats
    float* out_f32 = y_f32 + (size_t)NB * NV;       // 32768
    float* h_f32   = out_f32 + (size_t)NB * ND;     // 32768
    float* c_f32   = h_f32 + (size_t)NB * ND;       // 32768

    // The y slot (2,048,000 f32 = 8.19 MB) doubles as scratch; every region is
    // dead before k_logits overwrites the whole slot with f32 logits:
    //   [0      .. 131072)  gatePre   (k_gates  -> k_lstm)
    //   [0      .. 524288)  partZ     (k_attn   -> k_zcomb, overwrites dead gatePre)
    //   [600000 .. 632768)  bvec      (k_we     -> k_attn)
    //   [700000 .. 732768)  zctx      (k_zcomb  -> k_out)
    //   [800000 .. 801024)  partM     (k_attn   -> k_zcomb)
    //   [801024 .. 802048)  partS     (k_attn   -> k_zcomb)
    //   [900000 .. 900064)  tok (int) (k_argmax -> k_gates)
    float* gatePre = y_f32;
    float* partZ   = y_f32;
    float* bvec    = y_f32 + 600000;
    float* zctx    = y_f32 + 700000;
    float* partM   = y_f32 + 800000;
    float* partS   = y_f32 + 801024;
    int*   tok     = (int*)(y_f32 + 900000);

    k_argmax<<<NB, 256, 0, stream>>>(y_prev, tok);
    k_gates<<<dim3(8, 16), 256, 0, stream>>>(embedding, out_prev, tok, W_f, W_i, W_g, W_o, gatePre);
    k_lstm<<<128, 256, 0, stream>>>(gatePre, c_prev, b_f, b_i, b_g, b_o, h_f32, c_f32);
    k_we<<<dim3(2, 16), 256, 0, stream>>>(h_f32, W_e, bvec);
    k_attn<<<NB * CHUNKS, 256, 0, stream>>>(featureGrid, bvec, partM, partS, partZ);
    k_zcomb<<<NB, 256, 0, stream>>>(partM, partS, partZ, zctx);
    k_out<<<dim3(2, 16), 256, 0, stream>>>(h_f32, zctx, W_out, out_f32);
    k_logits<<<250, 256, 0, stream>>>(out_f32, W_y, y_f32);
    k_softmax<<<NB, 256, 0, stream>>>(y_f32);
}

// Round 4
// 400.253 us; speedup vs baseline: 1.5607x; 1.5607x over previous
//
#include <hip/hip_runtime.h>
#include <math.h>

#define NB 64
#define NL 4096
#define ND 512
#define NE 256
#define NV 32000
#define NX 768            // NE + ND
#define CHUNKS 32         // attention L-chunks per batch
#define RPC (NL / CHUNKS) // 128 rows per chunk
#define RPW (RPC / 4)     // 32 rows per wave
#define NV4 (NV / 4)      // 8000 float4 per vocab row

// ---------------------------------------------------------------- argmax ----
// 1024 threads, float4 loads, first-max semantics.
__global__ void k_argmax(const float* __restrict__ y_prev, int* __restrict__ tok) {
    int b = blockIdx.x, tid = threadIdx.x, lane = tid & 63, wave = tid >> 6;
    const float4* row = (const float4*)(y_prev + (size_t)b * NV);
    float best = -INFINITY; int bi = 0x7fffffff;
    for (int v4 = tid; v4 < NV4; v4 += 1024) {
        float4 x = row[v4];
        int base = v4 * 4;
        if (x.x > best) { best = x.x; bi = base; }
        if (x.y > best) { best = x.y; bi = base + 1; }
        if (x.z > best) { best = x.z; bi = base + 2; }
        if (x.w > best) { best = x.w; bi = base + 3; }
    }
    #pragma unroll
    for (int off = 32; off > 0; off >>= 1) {
        float ob = __shfl_xor(best, off, 64);
        int   oi = __shfl_xor(bi, off, 64);
        if (ob > best || (ob == best && oi < bi)) { best = ob; bi = oi; }
    }
    __shared__ float sv[16]; __shared__ int si[16];
    if (lane == 0) { sv[wave] = best; si[wave] = bi; }
    __syncthreads();
    if (tid == 0) {
        float bb = sv[0]; int ii = si[0];
        for (int w = 1; w < 16; ++w)
            if (sv[w] > bb || (sv[w] == bb && si[w] < ii)) { bb = sv[w]; ii = si[w]; }
        tok[b] = ii;
    }
}

// ------------------------------------------------- gate GEMM (x @ W_fiog) ----
__global__ void k_gates(const float* __restrict__ embedding, const float* __restrict__ out_prev,
                        const int* __restrict__ tok,
                        const float* __restrict__ W_f, const float* __restrict__ W_i,
                        const float* __restrict__ W_g, const float* __restrict__ W_o,
                        float* __restrict__ gatePre /* [4][NB][ND] */) {
    __shared__ float xs[4][NX];
    int tid = threadIdx.x;
    int col = blockIdx.x * 256 + tid;   // 0..2047 (gate-uniform per block)
    int b0  = blockIdx.y * 4;
    for (int e = tid; e < 4 * NX; e += 256) {
        int g = e / NX, k = e - g * NX;
        int b = b0 + g;
        xs[g][k] = (k < NE) ? embedding[(size_t)tok[b] * NE + k]
                            : out_prev[(size_t)b * ND + (k - NE)];
    }
    __syncthreads();
    int gate = col >> 9, d = col & 511;
    const float* W = (gate == 0) ? W_f : (gate == 1) ? W_i : (gate == 2) ? W_g : W_o;
    float a0 = 0, a1 = 0, a2 = 0, a3 = 0;
    for (int k = 0; k < NX; ++k) {
        float w = W[(size_t)k * ND + d];
        a0 += xs[0][k] * w; a1 += xs[1][k] * w; a2 += xs[2][k] * w; a3 += xs[3][k] * w;
    }
    gatePre[((size_t)gate * NB + b0 + 0) * ND + d] = a0;
    gatePre[((size_t)gate * NB + b0 + 1) * ND + d] = a1;
    gatePre[((size_t)gate * NB + b0 + 2) * ND + d] = a2;
    gatePre[((size_t)gate * NB + b0 + 3) * ND + d] = a3;
}

// -------------------------------------------------------- LSTM pointwise ----
__global__ void k_lstm(const float* __restrict__ gatePre, const float* __restrict__ c_prev,
                       const float* __restrict__ b_f, const float* __restrict__ b_i,
                       const float* __restrict__ b_g, const float* __restrict__ b_o,
                       float* __restrict__ h_out, float* __restrict__ c_out) {
    int idx = blockIdx.x * 256 + threadIdx.x;  // 0..32767
    int b = idx >> 9, d = idx & 511;
    float F = gatePre[((size_t)0 * NB + b) * ND + d] + b_f[d];
    float I = gatePre[((size_t)1 * NB + b) * ND + d] + b_i[d];
    float G = gatePre[((size_t)2 * NB + b) * ND + d] + b_g[d];
    float O = gatePre[((size_t)3 * NB + b) * ND + d] + b_o[d];
    float f = 1.f / (1.f + __expf(-F));
    float i = 1.f / (1.f + __expf(-I));
    float g = tanhf(G);
    float o = 1.f / (1.f + __expf(-O));
    float c = c_prev[idx] * f + i * g;
    float h = tanhf(c) * o;
    h_out[idx] = h;
    c_out[idx] = c;
}

// ------------------------------------------------------- b = h @ W_e ---------
__global__ void k_we(const float* __restrict__ h, const float* __restrict__ W_e,
                     float* __restrict__ bvec) {
    __shared__ float hs[4][ND];
    int tid = threadIdx.x, col = blockIdx.x * 256 + tid, b0 = blockIdx.y * 4;
    for (int e = tid; e < 4 * ND; e += 256) { int g = e >> 9, k = e & 511; hs[g][k] = h[(size_t)(b0 + g) * ND + k]; }
    __syncthreads();
    float a0 = 0, a1 = 0, a2 = 0, a3 = 0;
    for (int k = 0; k < ND; ++k) {
        float w = W_e[(size_t)k * ND + col];
        a0 += hs[0][k] * w; a1 += hs[1][k] * w; a2 += hs[2][k] * w; a3 += hs[3][k] * w;
    }
    bvec[(size_t)(b0 + 0) * ND + col] = a0;
    bvec[(size_t)(b0 + 1) * ND + col] = a1;
    bvec[(size_t)(b0 + 2) * ND + col] = a2;
    bvec[(size_t)(b0 + 3) * ND + col] = a3;
}

// --------------------------- fused attention: online softmax + context ------
// grid NB*CHUNKS blocks, 256 thr (4 waves). Reads featureGrid exactly once.
__global__ void k_attn(const float* __restrict__ fg, const float* __restrict__ bvec,
                       float* __restrict__ partM, float* __restrict__ partS,
                       float* __restrict__ partZ) {
    int blk = blockIdx.x;
    int b = blk / CHUNKS, chunk = blk - b * CHUNKS;
    int tid = threadIdx.x, wave = tid >> 6, lane = tid & 63;
    float4 bs0 = ((const float4*)(bvec + (size_t)b * ND + lane * 8))[0];
    float4 bs1 = ((const float4*)(bvec + (size_t)b * ND + lane * 8))[1];
    const float* rowp = fg + ((size_t)b * NL + (size_t)chunk * RPC + wave * RPW) * ND + lane * 8;
    float m = -INFINITY, s = 0.f;
    float z0 = 0, z1 = 0, z2 = 0, z3 = 0, z4 = 0, z5 = 0, z6 = 0, z7 = 0;
    float4 v0 = ((const float4*)rowp)[0];
    float4 v1 = ((const float4*)rowp)[1];
    for (int r = 0; r < RPW; ++r) {
        float4 n0 = v0, n1 = v1;
        if (r + 1 < RPW) {  // prefetch next row
            const float* np = rowp + ND;
            n0 = ((const float4*)np)[0];
            n1 = ((const float4*)np)[1];
        }
        float e = v0.x * bs0.x + v0.y * bs0.y + v0.z * bs0.z + v0.w * bs0.w
                + v1.x * bs1.x + v1.y * bs1.y + v1.z * bs1.z + v1.w * bs1.w;
        #pragma unroll
        for (int off = 32; off > 0; off >>= 1) e += __shfl_xor(e, off, 64);
        // branchless online-softmax update
        float mn = fmaxf(m, e);
        float sc = __expf(m - mn);   // m=-inf -> 0
        float w  = __expf(e - mn);
        s = s * sc + w;
        z0 = z0 * sc + w * v0.x; z1 = z1 * sc + w * v0.y;
        z2 = z2 * sc + w * v0.z; z3 = z3 * sc + w * v0.w;
        z4 = z4 * sc + w * v1.x; z5 = z5 * sc + w * v1.y;
        z6 = z6 * sc + w * v1.z; z7 = z7 * sc + w * v1.w;
        m = mn;
        rowp += ND; v0 = n0; v1 = n1;
    }
    __shared__ float wm[4], wsum[4], wz[4][ND];
    float* zp = &wz[wave][lane * 8];
    zp[0] = z0; zp[1] = z1; zp[2] = z2; zp[3] = z3; zp[4] = z4; zp[5] = z5; zp[6] = z6; zp[7] = z7;
    if (lane == 0) { wm[wave] = m; wsum[wave] = s; }
    __syncthreads();
    float M = fmaxf(fmaxf(wm[0], wm[1]), fmaxf(wm[2], wm[3]));
    float e0 = __expf(wm[0] - M), e1 = __expf(wm[1] - M), e2 = __expf(wm[2] - M), e3 = __expf(wm[3] - M);
    if (tid == 0) {
        partM[blk] = M;
        partS[blk] = wsum[0] * e0 + wsum[1] * e1 + wsum[2] * e2 + wsum[3] * e3;
    }
    for (int d = tid; d < ND; d += 256)
        partZ[(size_t)blk * ND + d] = wz[0][d] * e0 + wz[1][d] * e1 + wz[2][d] * e2 + wz[3][d] * e3;
}

// ---------------------------------------------- combine chunk partials → z --
__global__ void k_zcomb(const float* __restrict__ partM, const float* __restrict__ partS,
                        const float* __restrict__ partZ, float* __restrict__ z) {
    int b = blockIdx.x, tid = threadIdx.x;
    float M = -INFINITY;
    #pragma unroll
    for (int j = 0; j < CHUNKS; ++j) M = fmaxf(M, partM[b * CHUNKS + j]);
    float w[CHUNKS]; float S = 0.f;
    #pragma unroll
    for (int j = 0; j < CHUNKS; ++j) { w[j] = __expf(partM[b * CHUNKS + j] - M); S += partS[b * CHUNKS + j] * w[j]; }
    float inv = 1.f / S;
    for (int d = tid; d < ND; d += 256) {
        float acc = 0.f;
        #pragma unroll
        for (int j = 0; j < CHUNKS; ++j) acc += w[j] * partZ[((size_t)b * CHUNKS + j) * ND + d];
        z[(size_t)b * ND + d] = acc * inv;
    }
}

// ------------------------------------------- out = tanh([h,z] @ W_out) ------
// Writes out (coalesced) AND outT[512][64] (for coalesced k_logits staging).
__global__ void k_out(const float* __restrict__ h, const float* __restrict__ z,
                      const float* __restrict__ W_out,
                      float* __restrict__ out_f32, float* __restrict__ outT) {
    __shared__ float hzs[4][2 * ND];
    int tid = threadIdx.x, col = blockIdx.x * 256 + tid, b0 = blockIdx.y * 4;
    for (int e = tid; e < 4 * 2 * ND; e += 256) {
        int g = e >> 10, k = e & 1023; int b = b0 + g;
        hzs[g][k] = (k < ND) ? h[(size_t)b * ND + k] : z[(size_t)b * ND + (k - ND)];
    }
    __syncthreads();
    float a0 = 0, a1 = 0, a2 = 0, a3 = 0;
    for (int k = 0; k < 2 * ND; ++k) {
        float w = W_out[(size_t)k * ND + col];
        a0 += hzs[0][k] * w; a1 += hzs[1][k] * w; a2 += hzs[2][k] * w; a3 += hzs[3][k] * w;
    }
    float t0 = tanhf(a0), t1 = tanhf(a1), t2 = tanhf(a2), t3 = tanhf(a3);
    out_f32[(size_t)(b0 + 0) * ND + col] = t0;
    out_f32[(size_t)(b0 + 1) * ND + col] = t1;
    out_f32[(size_t)(b0 + 2) * ND + col] = t2;
    out_f32[(size_t)(b0 + 3) * ND + col] = t3;
    outT[(size_t)col * NB + b0 + 0] = t0;
    outT[(size_t)col * NB + b0 + 1] = t1;
    outT[(size_t)col * NB + b0 + 2] = t2;
    outT[(size_t)col * NB + b0 + 3] = t3;
}

// --------------------------------------------- logits = out @ W_y -----------
// grid (250, 2): 128 cols x 32 batches per block; thread tile 4b x 4c.
// Reads outT coalesced; writes f32 logits into the y slot of d_out.
__global__ void k_logits(const float* __restrict__ outT, const float* __restrict__ W_y,
                         float* __restrict__ ylog) {
    __shared__ float os[64][32];  // [dd][b]
    int tid = threadIdx.x;
    int cg = tid & 31;            // 32 col-groups x 4 cols
    int bg = tid >> 5;            // 8 batch-groups x 4 batches
    int c0 = blockIdx.x * 128 + cg * 4;
    int b0 = blockIdx.y * 32;
    float acc[4][4];
    #pragma unroll
    for (int i = 0; i < 4; ++i)
        #pragma unroll
        for (int j = 0; j < 4; ++j) acc[i][j] = 0.f;
    for (int dt = 0; dt < 8; ++dt) {
        if (dt) __syncthreads();
        for (int e = tid; e < 2048; e += 256) {
            int dd = e >> 5, bb = e & 31;
            os[dd][bb] = outT[(size_t)(dt * 64 + dd) * NB + b0 + bb];
        }
        __syncthreads();
        for (int dd = 0; dd < 64; ++dd) {
            float4 wv = *(const float4*)&W_y[(size_t)(dt * 64 + dd) * NV + c0];
            float4 ov = *(const float4*)&os[dd][bg * 4];
            const float wj[4] = {wv.x, wv.y, wv.z, wv.w};
            const float ob[4] = {ov.x, ov.y, ov.z, ov.w};
            #pragma unroll
            for (int i = 0; i < 4; ++i)
                #pragma unroll
                for (int j = 0; j < 4; ++j) acc[i][j] += ob[i] * wj[j];
        }
    }
    #pragma unroll
    for (int i = 0; i < 4; ++i) {
        float4 st = make_float4(acc[i][0], acc[i][1], acc[i][2], acc[i][3]);
        *(float4*)&ylog[(size_t)(b0 + bg * 4 + i) * NV + c0] = st;
    }
}

// ------------------- softmax in place, row data held in registers -----------
// 64 blocks x 1024 thr; each thread owns <=8 float4 of the row.
__global__ void k_softmax(float* __restrict__ y) {
    int b = blockIdx.x, tid = threadIdx.x, lane = tid & 63, wave = tid >> 6;
    float4* row = (float4*)(y + (size_t)b * NV);
    float4 r[8];
    int cnt = 0;
    for (int v4 = tid; v4 < NV4; v4 += 1024) r[cnt++] = row[v4];
    // --- max ---
    float m = -INFINITY;
    for (int k = 0; k < cnt; ++k)
        m = fmaxf(m, fmaxf(fmaxf(r[k].x, r[k].y), fmaxf(r[k].z, r[k].w)));
    #pragma unroll
    for (int off = 32; off > 0; off >>= 1) m = fmaxf(m, __shfl_xor(m, off, 64));
    __shared__ float red[16];
    __shared__ float bcast[2];
    if (lane == 0) red[wave] = m;
    __syncthreads();
    if (tid == 0) {
        float M = red[0];
        for (int w = 1; w < 16; ++w) M = fmaxf(M, red[w]);
        bcast[0] = M;
    }
    __syncthreads();
    float M = bcast[0];
    // --- exp + sum (in registers) ---
    float s = 0.f;
    for (int k = 0; k < cnt; ++k) {
        r[k].x = __expf(r[k].x - M); r[k].y = __expf(r[k].y - M);
        r[k].z = __expf(r[k].z - M); r[k].w = __expf(r[k].w - M);
        s += r[k].x + r[k].y + r[k].z + r[k].w;
    }
    #pragma unroll
    for (int off = 32; off > 0; off >>= 1) s += __shfl_xor(s, off, 64);
    if (lane == 0) red[wave] = s;
    __syncthreads();
    if (tid == 0) {
        float S = 0.f;
        for (int w = 0; w < 16; ++w) S += red[w];
        bcast[1] = 1.f / S;
    }
    __syncthreads();
    float inv = bcast[1];
    // --- scale + store ---
    cnt = 0;
    for (int v4 = tid; v4 < NV4; v4 += 1024) {
        float4 e4 = r[cnt++];
        e4.x *= inv; e4.y *= inv; e4.z *= inv; e4.w *= inv;
        row[v4] = e4;
    }
}

// ---------------------------------------------------------------------------
extern "C" void kernel_launch(void* const* d_in, const int* in_sizes, int n_in,
                              void* d_out, int out_size, void* d_ws, size_t ws_size,
                              hipStream_t stream) {
    (void)in_sizes; (void)n_in; (void)out_size; (void)ws_size;
    const float* featureGrid = (const float*)d_in[0];
    const float* y_prev      = (const float*)d_in[1];
    const float* out_prev    = (const float*)d_in[2];
    // d_in[3] = h_prev (unused by the reference)
    const float* c_prev      = (const float*)d_in[4];
    const float* embedding   = (const float*)d_in[5];
    const float* W_f = (const float*)d_in[6];
    const float* W_i = (const float*)d_in[7];
    const float* W_g = (const float*)d_in[8];
    const float* W_o = (const float*)d_in[9];
    const float* b_f = (const float*)d_in[10];
    const float* b_i = (const float*)d_in[11];
    const float* b_g = (const float*)d_in[12];
    const float* b_o = (const float*)d_in[13];
    const float* W_e   = (const float*)d_in[14];
    const float* W_out = (const float*)d_in[15];
    const float* W_y   = (const float*)d_in[16];

    // d_out: flat f32, return order: y [64*32000] | out [64*512] | h | c
    float* y_f32   = (float*)d_out;                 // 2,048,000 floats
    float* out_f32 = y_f32 + (size_t)NB * NV;       // 32768
    float* h_f32   = out_f32 + (size_t)NB * ND;     // 32768
    float* c_f32   = h_f32 + (size_t)NB * ND;       // 32768

    // All scratch in d_ws (poison fills show ws_size = 2 GiB; we use 5.1 MB).
    float* ws = (float*)d_ws;
    int*   tok     = (int*)ws;                         // 64
    float* gatePre = ws + 64;                          // 131072
    float* bvec    = gatePre + 131072;                 // 32768  (16B-aligned)
    float* zctx    = bvec + 32768;                     // 32768
    float* partM   = zctx + 32768;                     // 2048
    float* partS   = partM + NB * CHUNKS;              // 2048
    float* partZ   = partS + NB * CHUNKS;              // 1,048,576 (16B-aligned)
    float* outT    = partZ + (size_t)NB * CHUNKS * ND; // 32768

    k_argmax<<<NB, 1024, 0, stream>>>(y_prev, tok);
    k_gates<<<dim3(8, 16), 256, 0, stream>>>(embedding, out_prev, tok, W_f, W_i, W_g, W_o, gatePre);
    k_lstm<<<128, 256, 0, stream>>>(gatePre, c_prev, b_f, b_i, b_g, b_o, h_f32, c_f32);
    k_we<<<dim3(2, 16), 256, 0, stream>>>(h_f32, W_e, bvec);
    k_attn<<<NB * CHUNKS, 256, 0, stream>>>(featureGrid, bvec, partM, partS, partZ);
    k_zcomb<<<NB, 256, 0, stream>>>(partM, partS, partZ, zctx);
    k_out<<<dim3(2, 16), 256, 0, stream>>>(h_f32, zctx, W_out, out_f32, outT);
    k_logits<<<dim3(250, 2), 256, 0, stream>>>(outT, W_y, y_f32);
    k_softmax<<<NB, 1024, 0, stream>>>(y_f32);
}